// Round 7
// baseline (189.910 us; speedup 1.0000x reference)
//
#include <hip/hip_runtime.h>

#define BB 128
#define LL 256
#define DD 384
#define QB 64

typedef __attribute__((ext_vector_type(8))) _Float16 half8;
typedef __attribute__((ext_vector_type(4))) float f32x4;
typedef __attribute__((ext_vector_type(4))) uint  u32x4;

union fragh { u32x4 u; half8 h; };

__device__ inline uint packrne(float a, float b) {
  _Float16 ha = (_Float16)a, hb = (_Float16)b;   // v_cvt_f16_f32 (RNE)
  return (uint)__builtin_bit_cast(unsigned short, ha) |
         ((uint)__builtin_bit_cast(unsigned short, hb) << 16);
}

__device__ inline unsigned short f16b(float x) {
  _Float16 h = (_Float16)x;
  return __builtin_bit_cast(unsigned short, h);
}

// 8-half fragment from two 8B LDS reads (rows 72B-strided, 8B-aligned)
__device__ inline half8 ld_frag8h(const short* p) {
  uint2 lo = *(const uint2*)p;
  uint2 hi = *(const uint2*)(p + 4);
  fragh f;
  f.u[0] = lo.x; f.u[1] = lo.y; f.u[2] = hi.x; f.u[3] = hi.y;
  return f.h;
}

#define MFMA16 __builtin_amdgcn_mfma_f32_16x16x32_f16

// ---------------- K1: S = q . a^T (fp16 MFMA) + row stats + col partial stats ----------------
// One block per (b, q-tile). 512 thr = 8 waves, wave-grid 1x8 over 64x256.
__global__ __launch_bounds__(512, 5) void scores_stats_kernel(
    const float* __restrict__ qf, const float* __restrict__ af,
    float* __restrict__ S, float* __restrict__ partials, float* __restrict__ qstats)
{
  const int bid = blockIdx.x;            // 512 blocks: xcd = bid&7 = b&7
  const int blo = bid & 7, r1 = bid >> 3;
  const int qt = r1 & 3, bhi = r1 >> 2;
  const int b = bhi * 8 + blo;
  const int r0 = qt * QB;

  __shared__ __align__(16) short sF[LL][36];   // a_feat fp16 [256][32+pad]
  __shared__ __align__(16) short sS[QB][36];   // q rows fp16 [64][32+pad]
  __shared__ float sRedM[8][QB];
  __shared__ float sRedS[8][QB];

  const int t = threadIdx.x;
  const int w = t >> 6, lane = t & 63;
  const int lam = lane & 15, g = lane >> 4;

  const float* selfb = qf + ((size_t)b * LL + r0) * DD;
  const float* featb = af + (size_t)b * LL * DD;

  const int tok8 = t >> 3;        // 0..63
  const int k4   = (t & 7) * 4;   // 0,4,..,28
  float4 fF[4], fS;

  #define LOADA(kc_) do {                                                         \
    const int k0_ = (kc_) * 32;                                                   \
    _Pragma("unroll")                                                             \
    for (int j = 0; j < 4; ++j)                                                   \
      fF[j] = *(const float4*)&featb[(size_t)(tok8 + 64 * j) * DD + k0_ + k4];    \
    fS = *(const float4*)&selfb[(size_t)tok8 * DD + k0_ + k4];                    \
  } while (0)

  f32x4 accS[4][2] = {};
  LOADA(0);
  for (int kc = 0; kc < 12; ++kc) {
    #pragma unroll
    for (int j = 0; j < 4; ++j) {
      uint2 p = make_uint2(packrne(fF[j].x, fF[j].y), packrne(fF[j].z, fF[j].w));
      *(uint2*)&sF[tok8 + 64 * j][k4] = p;
    }
    {
      uint2 p = make_uint2(packrne(fS.x, fS.y), packrne(fS.z, fS.w));
      *(uint2*)&sS[tok8][k4] = p;
    }
    __syncthreads();
    if (kc < 11) LOADA(kc + 1);
    half8 ah[4], bh[2];
    #pragma unroll
    for (int rt = 0; rt < 4; ++rt) ah[rt] = ld_frag8h(&sS[rt * 16 + lam][g * 8]);
    #pragma unroll
    for (int ct = 0; ct < 2; ++ct) bh[ct] = ld_frag8h(&sF[w * 32 + ct * 16 + lam][g * 8]);
    __builtin_amdgcn_s_setprio(1);
    #pragma unroll
    for (int rt = 0; rt < 4; ++rt)
      #pragma unroll
      for (int ct = 0; ct < 2; ++ct)
        accS[rt][ct] = MFMA16(ah[rt], bh[ct], accS[rt][ct], 0, 0, 0);
    __builtin_amdgcn_s_setprio(0);
    __syncthreads();
  }

  // ---- q-row max (cross-wave) ----
  #pragma unroll
  for (int rt = 0; rt < 4; ++rt)
    #pragma unroll
    for (int rg = 0; rg < 4; ++rg) {
      float m = fmaxf(accS[rt][0][rg], accS[rt][1][rg]);
      #pragma unroll
      for (int off = 1; off < 16; off <<= 1) m = fmaxf(m, __shfl_xor(m, off));
      if (lam == 0) sRedM[w][rt * 16 + g * 4 + rg] = m;
    }
  __syncthreads();
  float mrow[4][4];
  #pragma unroll
  for (int rt = 0; rt < 4; ++rt)
    #pragma unroll
    for (int rg = 0; rg < 4; ++rg) {
      int row = rt * 16 + g * 4 + rg;
      float m = sRedM[0][row];
      #pragma unroll
      for (int ww = 1; ww < 8; ++ww) m = fmaxf(m, sRedM[ww][row]);
      mrow[rt][rg] = m;
    }

  // ---- store raw S (fp32, coalesced 64B row-chunks) ----
  #pragma unroll
  for (int rt = 0; rt < 4; ++rt)
    #pragma unroll
    for (int ct = 0; ct < 2; ++ct)
      #pragma unroll
      for (int rg = 0; rg < 4; ++rg)
        S[((size_t)b * LL + r0 + rt * 16 + g * 4 + rg) * LL + w * 32 + ct * 16 + lam]
            = accS[rt][ct][rg];

  // ---- a-side column partial stats (flash combine inputs) ----
  #pragma unroll
  for (int ct = 0; ct < 2; ++ct) {
    float m = -1e30f;
    #pragma unroll
    for (int rt = 0; rt < 4; ++rt)
      #pragma unroll
      for (int rg = 0; rg < 4; ++rg) m = fmaxf(m, accS[rt][ct][rg]);
    m = fmaxf(m, __shfl_xor(m, 16));
    m = fmaxf(m, __shfl_xor(m, 32));
    float l = 0.f;
    #pragma unroll
    for (int rt = 0; rt < 4; ++rt)
      #pragma unroll
      for (int rg = 0; rg < 4; ++rg) l += __expf(accS[rt][ct][rg] - m);
    l += __shfl_xor(l, 16);
    l += __shfl_xor(l, 32);
    if (g == 0) {
      int c = w * 32 + ct * 16 + lam;
      partials[(((size_t)b * 4 + qt) * 2 + 0) * LL + c] = m;
      partials[(((size_t)b * 4 + qt) * 2 + 1) * LL + c] = l;
    }
  }

  // ---- q-row sum of exp (cross-wave) ----
  #pragma unroll
  for (int rt = 0; rt < 4; ++rt)
    #pragma unroll
    for (int rg = 0; rg < 4; ++rg) {
      float s = 0.f;
      #pragma unroll
      for (int ct = 0; ct < 2; ++ct) s += __expf(accS[rt][ct][rg] - mrow[rt][rg]);
      #pragma unroll
      for (int off = 1; off < 16; off <<= 1) s += __shfl_xor(s, off);
      if (lam == 0) sRedS[w][rt * 16 + g * 4 + rg] = s;
    }
  __syncthreads();
  if (t < QB) {
    float m = sRedM[0][t], l = 0.f;
    #pragma unroll
    for (int ww = 1; ww < 8; ++ww) m = fmaxf(m, sRedM[ww][t]);
    #pragma unroll
    for (int ww = 0; ww < 8; ++ww) l += sRedS[ww][t];
    qstats[((size_t)b * 2 + 0) * LL + r0 + t] = m;
    qstats[((size_t)b * 2 + 1) * LL + r0 + t] = l;
  }
}

// ---------------- K2: P(from S,stats) @ feat -> l2norm -> masked pool ----------------
// One block per (b, side, 64-row tile). 512 thr = 8 waves, wave-grid 1x8.
__global__ __launch_bounds__(512, 4) void pv_pool_kernel(
    const float* __restrict__ qf, const float* __restrict__ af,
    const int* __restrict__ qm, const int* __restrict__ am,
    const float* __restrict__ S, const float* __restrict__ partials,
    const float* __restrict__ qstats, float* __restrict__ accum)
{
  const int bid = blockIdx.x;            // 1024 blocks: xcd = bid&7 = b&7
  const int blo = bid & 7, r1 = bid >> 3;
  const int tl = r1 & 7, bhi = r1 >> 3;
  const int b = bhi * 8 + blo;
  const int side = tl >> 2, r0 = (tl & 3) * QB;

  const float* self = side ? af : qf;
  const float* feat = side ? qf : af;
  const int*   msk  = side ? am : qm;

  __shared__ __align__(16) short sVt[DD][36];           // featT fp16 chunk
  __shared__ __align__(16) unsigned short sP[4][QB][8]; // P fp16, frag layout, per chunk
  __shared__ float sM[QB], sLi[QB];
  __shared__ float sRedM[8][QB];
  __shared__ float sInv[QB];
  __shared__ float sSsq[QB];
  __shared__ float sPool[DD];

  const int t = threadIdx.x;
  const int w = t >> 6, lane = t & 63;
  const int lam = lane & 15, g = lane >> 4;

  const float* selfb = self + ((size_t)b * LL + r0) * DD;
  const float* featb = feat + (size_t)b * LL * DD;
  const float* Sb    = S + (size_t)b * LL * LL;

  // ---- per-row softmax stats ----
  if (t < QB) {
    float m, l;
    if (side == 0) {
      m = qstats[((size_t)b * 2 + 0) * LL + r0 + t];
      l = qstats[((size_t)b * 2 + 1) * LL + r0 + t];
    } else {
      int c = r0 + t;
      float mp[4], lp[4];
      #pragma unroll
      for (int p = 0; p < 4; ++p) {
        mp[p] = partials[(((size_t)b * 4 + p) * 2 + 0) * LL + c];
        lp[p] = partials[(((size_t)b * 4 + p) * 2 + 1) * LL + c];
      }
      m = fmaxf(fmaxf(mp[0], mp[1]), fmaxf(mp[2], mp[3]));
      l = 0.f;
      #pragma unroll
      for (int p = 0; p < 4; ++p) l += lp[p] * __expf(mp[p] - m);
    }
    sM[t] = m;
    sLi[t] = 1.f / l;
  }
  __syncthreads();

  f32x4 accP[4][3] = {};
  for (int ac = 0; ac < 8; ++ac) {
    const int k0 = ac * 32;
    // ---- stage featT[d][tok] fp16 (consecutive-d mapping: 2-way-free writes) ----
    #pragma unroll
    for (int i = 0; i < 12; ++i) {
      int s = t + i * 512;                 // 6144 u32 slots
      int kp = s / 384, d = s - kp * 384;  // kp: token-pair 0..15
      float s0 = featb[(size_t)(k0 + kp * 2) * DD + d];
      float s1 = featb[(size_t)(k0 + kp * 2 + 1) * DD + d];
      *(uint*)&sVt[d][kp * 2] = packrne(s0, s1);
    }
    // ---- stage P chunk from S + stats ----
    if (side == 0) {
      int q = t >> 3, a0 = (t & 7) * 4;
      float4 sv = *(const float4*)&Sb[(size_t)(r0 + q) * LL + k0 + a0];
      float m = sM[q], li = sLi[q];
      uint2 pk = make_uint2(
          (uint)f16b(__expf(sv.x - m) * li) | ((uint)f16b(__expf(sv.y - m) * li) << 16),
          (uint)f16b(__expf(sv.z - m) * li) | ((uint)f16b(__expf(sv.w - m) * li) << 16));
      *(uint2*)&sP[(t & 7) >> 1][q][(t & 1) * 4] = pk;
    } else {
      int qq = t >> 4, la0 = (t & 15) * 4;     // q token in chunk, local a row
      float4 sv = *(const float4*)&Sb[(size_t)(k0 + qq) * LL + r0 + la0];
      const float* svp = (const float*)&sv;
      #pragma unroll
      for (int j = 0; j < 4; ++j) {
        float e = __expf(svp[j] - sM[la0 + j]) * sLi[la0 + j];
        sP[qq >> 3][la0 + j][qq & 7] = f16b(e);
      }
    }
    __syncthreads();
    fragh pf[4];
    half8 vf[3];
    #pragma unroll
    for (int rt = 0; rt < 4; ++rt)
      pf[rt].u = *(const u32x4*)&sP[g][rt * 16 + lam][0];
    #pragma unroll
    for (int dt = 0; dt < 3; ++dt)
      vf[dt] = ld_frag8h(&sVt[w * 48 + dt * 16 + lam][g * 8]);
    __builtin_amdgcn_s_setprio(1);
    #pragma unroll
    for (int rt = 0; rt < 4; ++rt)
      #pragma unroll
      for (int dt = 0; dt < 3; ++dt)
        accP[rt][dt] = MFMA16(pf[rt].h, vf[dt], accP[rt][dt], 0, 0, 0);
    __builtin_amdgcn_s_setprio(0);
    __syncthreads();
  }

  // ---- epilogue: row l2norm over [self|attended], masked pool ----
  #pragma unroll
  for (int rt = 0; rt < 4; ++rt)
    #pragma unroll
    for (int rg = 0; rg < 4; ++rg) {
      float s = 0.f;
      #pragma unroll
      for (int dt = 0; dt < 3; ++dt) s += accP[rt][dt][rg] * accP[rt][dt][rg];
      #pragma unroll
      for (int off = 1; off < 16; off <<= 1) s += __shfl_xor(s, off);
      if (lam == 0) sRedM[w][rt * 16 + g * 4 + rg] = s;
    }
  {
    int sr = t >> 3, sc = (t & 7) * 4;
    const float* sp = &selfb[(size_t)sr * DD];
    float ss = 0.f;
    #pragma unroll
    for (int j = 0; j < 12; ++j) {
      float4 v = *(const float4*)&sp[sc + j * 32];
      ss += v.x * v.x + v.y * v.y + v.z * v.z + v.w * v.w;
    }
    ss += __shfl_xor(ss, 1); ss += __shfl_xor(ss, 2); ss += __shfl_xor(ss, 4);
    if ((t & 7) == 0) sSsq[sr] = ss;
  }
  __syncthreads();
  if (t < QB) {
    float tot = sSsq[t];
    #pragma unroll
    for (int ww = 0; ww < 8; ++ww) tot += sRedM[ww][t];
    int mv = msk[(size_t)b * LL + r0 + t];
    sInv[t] = mv ? (1.f / fmaxf(sqrtf(tot), 1e-12f)) : 0.f;
  }
  __syncthreads();
  #pragma unroll
  for (int dt = 0; dt < 3; ++dt) {
    float pa = 0.f;
    #pragma unroll
    for (int rt = 0; rt < 4; ++rt)
      #pragma unroll
      for (int rg = 0; rg < 4; ++rg)
        pa += sInv[rt * 16 + g * 4 + rg] * accP[rt][dt][rg];
    pa += __shfl_xor(pa, 16);
    pa += __shfl_xor(pa, 32);
    if (g == 0) sPool[w * 48 + dt * 16 + lam] = pa;
  }
  __syncthreads();
  if (t < DD) {
    float* ac = accum + ((size_t)side * BB + b) * 2 * DD;
    float ps = 0.f;
    const float* sp = selfb + t;
    #pragma unroll 4
    for (int r = 0; r < QB; ++r) ps = fmaf(sInv[r], sp[(size_t)r * DD], ps);
    atomicAdd(&ac[t], ps);
    atomicAdd(&ac[DD + t], sPool[t]);
  }
}

// ---------------- Finalize: divide by mask count, final l2norm ----------------
__global__ __launch_bounds__(256) void finalize_kernel(
    const float* __restrict__ accum, const int* __restrict__ qm,
    const int* __restrict__ am, float* __restrict__ out)
{
  const int b    = blockIdx.x & (BB - 1);
  const int side = blockIdx.x >> 7;
  const int* msk = side ? am : qm;
  const int t = threadIdx.x;
  __shared__ float red[8];

  float c = (float)msk[(size_t)b * LL + t];
  #pragma unroll
  for (int off = 1; off < 64; off <<= 1) c += __shfl_xor(c, off);
  if ((t & 63) == 0) red[t >> 6] = c;
  __syncthreads();
  float cnt = fmaxf(red[0] + red[1] + red[2] + red[3], 1e-9f);

  const float* ac = accum + ((size_t)side * BB + b) * 2 * DD;
  float v[3];
  float ssq = 0.f;
  #pragma unroll
  for (int i = 0; i < 3; ++i) {
    v[i] = ac[t * 3 + i] / cnt;
    ssq += v[i] * v[i];
  }
  #pragma unroll
  for (int off = 1; off < 64; off <<= 1) ssq += __shfl_xor(ssq, off);
  __syncthreads();
  if ((t & 63) == 0) red[t >> 6] = ssq;
  __syncthreads();
  float n = sqrtf(red[0] + red[1] + red[2] + red[3]);
  float inv = 1.f / fmaxf(n, 1e-12f);
  float* ob = out + ((size_t)side * BB + b) * 2 * DD;
  #pragma unroll
  for (int i = 0; i < 3; ++i) ob[t * 3 + i] = v[i] * inv;
}

extern "C" void kernel_launch(void* const* d_in, const int* in_sizes, int n_in,
                              void* d_out, int out_size, void* d_ws, size_t ws_size,
                              hipStream_t stream) {
  const float* qf = (const float*)d_in[0];
  const float* af = (const float*)d_in[1];
  const int*   qm = (const int*)d_in[2];
  const int*   am = (const int*)d_in[3];
  float* out = (float*)d_out;

  float* S        = (float*)d_ws;                        // 128*256*256 f32 = 33.55 MB
  float* partials = S + (size_t)BB * LL * LL;            // 128*4*2*256   = 1.05 MB
  float* qstats   = partials + (size_t)BB * 4 * 2 * LL;  // 128*2*256     = 0.26 MB
  float* accum    = qstats + (size_t)BB * 2 * LL;        // 2*128*768     = 0.79 MB

  (void)hipMemsetAsync(accum, 0, sizeof(float) * 2 * BB * 2 * DD, stream);
  scores_stats_kernel<<<dim3(512), 512, 0, stream>>>(qf, af, S, partials, qstats);
  pv_pool_kernel<<<dim3(1024), 512, 0, stream>>>(qf, af, qm, am, S, partials, qstats, accum);
  finalize_kernel<<<256, 256, 0, stream>>>(accum, qm, am, out);
}

// Round 9
// 114.268 us; speedup vs baseline: 1.6620x; 1.6620x over previous
//
#include <hip/hip_runtime.h>

#define BB 128
#define LL 256
#define DD 384
#define QB 64

typedef __attribute__((ext_vector_type(8))) _Float16 half8;
typedef __attribute__((ext_vector_type(4))) float f32x4;
typedef __attribute__((ext_vector_type(4))) uint  u32x4;

union fragh { u32x4 u; half8 h; };

__device__ inline uint packrne(float a, float b) {
  _Float16 ha = (_Float16)a, hb = (_Float16)b;   // v_cvt_f16_f32 (RNE)
  return (uint)__builtin_bit_cast(unsigned short, ha) |
         ((uint)__builtin_bit_cast(unsigned short, hb) << 16);
}

__device__ inline uint packrtz(float a, float b) {
  auto h = __builtin_amdgcn_cvt_pkrtz(a, b);   // one v_cvt_pkrtz_f16_f32
  return __builtin_bit_cast(uint, h);
}

// 8-half fragment from two 8B LDS reads (rows 72B-strided, 8B-aligned)
__device__ inline half8 ld_frag8h(const short* p) {
  uint2 lo = *(const uint2*)p;
  uint2 hi = *(const uint2*)(p + 4);
  fragh f;
  f.u[0] = lo.x; f.u[1] = lo.y; f.u[2] = hi.x; f.u[3] = hi.y;
  return f.h;
}

// 8-half fragment from fp32 LDS row (32 floats, 128B stride, granule-XOR swizzled)
__device__ inline half8 frag_f32(const float* rowp, int g, int key) {
  f32x4 a = *(const f32x4*)(rowp + (((2 * g)     ^ key) << 2));
  f32x4 b = *(const f32x4*)(rowp + (((2 * g + 1) ^ key) << 2));
  fragh f;
  f.u[0] = packrtz(a[0], a[1]); f.u[1] = packrtz(a[2], a[3]);
  f.u[2] = packrtz(b[0], b[1]); f.u[3] = packrtz(b[2], b[3]);
  return f.h;
}

#define MFMA16 __builtin_amdgcn_mfma_f32_16x16x32_f16

typedef const __attribute__((address_space(1))) uint ga_uint;
typedef __attribute__((address_space(3))) uint ls_uint;

// One block per (batch, side, 64-row tile). 512 threads = 8 waves, wave-grid 1x8.
__global__ __launch_bounds__(512, 4) void fused_kernel(
    const float* __restrict__ qf, const float* __restrict__ af,
    const int* __restrict__ qm, const int* __restrict__ am,
    float* __restrict__ accum)
{
  // XCD-affine decode: xcd = bid&7 = b&7 -> all 8 tiles of a batch on one XCD
  const int bid = blockIdx.x;
  const int blo = bid & 7, r1 = bid >> 3;
  const int tl = r1 & 7, bhi = r1 >> 3;
  const int b = bhi * 8 + blo;
  const int side = tl >> 2, r0 = (tl & 3) * QB;

  const float* self = side ? af : qf;   // rows we attend FROM
  const float* feat = side ? qf : af;   // rows we attend TO
  const int*   msk  = side ? am : qm;

  // LDS: 32768 + 8192 + 32768 + 2048*2 + 256*2 + 1536 = 79872 -> 2 blocks/CU
  __shared__ __align__(16) float sBig[LL * 32];     // PhaseA: feat fp32 [256][32] (gll dest, linear)
                                                    // PV: sVt fp16 [384][36] overlay (27648B)
  __shared__ __align__(16) float sS32[QB * 32];     // PhaseA: self fp32 [64][32]
  __shared__ __align__(16) short sAl[32 * QB * 8];  // 32KB: P fp16, A-frag layout [c8][row][8]
  __shared__ float sRedM[8][QB];
  __shared__ float sRedS[8][QB];
  __shared__ float sInv[QB];
  __shared__ float sSsq[QB];
  __shared__ float sPool[DD];

  short (*sVt)[36] = (short(*)[36])sBig;

  const int t = threadIdx.x;
  const int w = t >> 6, lane = t & 63;
  const int lam = lane & 15, g = lane >> 4;

  const float* selfb = self + ((size_t)b * LL + r0) * DD;
  const float* featb = feat + (size_t)b * LL * DD;

  // ---------------- Phase A: scores = self . feat^T via global_load_lds staging ----------------
  // gll dest is linear (base + lane*16); source granule pre-swizzled: srcg = p ^ (l>>3).
  // Read swizzle: granule q of row r lives at physical q ^ (r&7).
  const int keyw = lane >> 3;              // 0..7
  const int srcg = (lane & 7) ^ keyw;      // logical granule this lane supplies
  const int keyr = lam & 7;                // read-side XOR key (row & 7)

  f32x4 accS[4][2] = {};
  for (int kc = 0; kc < 12; ++kc) {
    const int k0 = kc * 32;
    #pragma unroll
    for (int it = 0; it < 4; ++it) {       // feat rows (w*4+it)*8 .. +8
      int rr = (w * 4 + it) * 8 + keyw;
      __builtin_amdgcn_global_load_lds(
          (ga_uint*)&featb[(size_t)rr * DD + k0 + srcg * 4],
          (ls_uint*)&sBig[(w * 4 + it) * 8 * 32], 16, 0, 0);
    }
    {                                       // self rows w*8 .. +8
      int rr = w * 8 + keyw;
      __builtin_amdgcn_global_load_lds(
          (ga_uint*)&selfb[(size_t)rr * DD + k0 + srcg * 4],
          (ls_uint*)&sS32[w * 8 * 32], 16, 0, 0);
    }
    __syncthreads();   // drains vmcnt (gll) before barrier -> data visible
    half8 ah[4], bh[2];
    #pragma unroll
    for (int rt = 0; rt < 4; ++rt)
      ah[rt] = frag_f32(&sS32[(rt * 16 + lam) * 32], g, keyr);
    #pragma unroll
    for (int ct = 0; ct < 2; ++ct)
      bh[ct] = frag_f32(&sBig[(w * 32 + ct * 16 + lam) * 32], g, keyr);
    __builtin_amdgcn_s_setprio(1);
    #pragma unroll
    for (int rt = 0; rt < 4; ++rt)
      #pragma unroll
      for (int ct = 0; ct < 2; ++ct)
        accS[rt][ct] = MFMA16(ah[rt], bh[ct], accS[rt][ct], 0, 0, 0);
    __builtin_amdgcn_s_setprio(0);
    __syncthreads();   // reads done before next chunk's gll writes
  }

  // ---------------- Softmax over cols (C layout: col=lane&15, row=g*4+rg) ----------------
  #pragma unroll
  for (int rt = 0; rt < 4; ++rt)
    #pragma unroll
    for (int rg = 0; rg < 4; ++rg) {
      float m = fmaxf(accS[rt][0][rg], accS[rt][1][rg]);
      #pragma unroll
      for (int off = 1; off < 16; off <<= 1) m = fmaxf(m, __shfl_xor(m, off));
      if (lam == 0) sRedM[w][rt * 16 + g * 4 + rg] = m;
    }
  __syncthreads();
  #pragma unroll
  for (int rt = 0; rt < 4; ++rt)
    #pragma unroll
    for (int rg = 0; rg < 4; ++rg) {
      int row = rt * 16 + g * 4 + rg;
      float m = sRedM[0][row];
      #pragma unroll
      for (int ww = 1; ww < 8; ++ww) m = fmaxf(m, sRedM[ww][row]);
      float s = 0.f;
      #pragma unroll
      for (int ct = 0; ct < 2; ++ct) {
        float p = __expf(accS[rt][ct][rg] - m);
        accS[rt][ct][rg] = p;
        s += p;
      }
      #pragma unroll
      for (int off = 1; off < 16; off <<= 1) s += __shfl_xor(s, off);
      if (lam == 0) sRedS[w][row] = s;
    }
  __syncthreads();
  #pragma unroll
  for (int rt = 0; rt < 4; ++rt)
    #pragma unroll
    for (int rg = 0; rg < 4; ++rg) {
      int row = rt * 16 + g * 4 + rg;
      float s = 0.f;
      #pragma unroll
      for (int ww = 0; ww < 8; ++ww) s += sRedS[ww][row];
      float inv = 1.f / s;
      #pragma unroll
      for (int ct = 0; ct < 2; ++ct) {
        int c = w * 32 + ct * 16 + lam;
        _Float16 ph = (_Float16)(accS[rt][ct][rg] * inv);
        sAl[((c >> 3) * QB + row) * 8 + (c & 7)] =
            (short)__builtin_bit_cast(unsigned short, ph);
      }
    }
  __syncthreads();

  // ---------------- PV: O[64][384] = P @ feat, granule-swizzled featT staging ----------------
  // wave w: d-cols w*48 + dt*16 + lam (dt=0..2)
  // physical granule = logical ^ sw, sw(d) = (d&1) | (((d>>4)&1)<<1)
  int   di[6], tgi[6];
  short* wp[6];
  #pragma unroll
  for (int i = 0; i < 6; ++i) {
    int u = t + i * 512;
    int tg = u / 384, d = u - tg * 384;
    di[i] = d; tgi[i] = tg;
    int sw = (d & 1) | (((d >> 4) & 1) << 1);
    wp[i] = &sVt[d][(((tg >> 1) ^ sw) << 3) + ((tg & 1) << 2)];
  }

  float v0[6], v1[6], v2[6], v3[6];
  #define LOADV(ac_) do {                                                          \
    const int k0_ = (ac_) * 32;                                                    \
    _Pragma("unroll")                                                              \
    for (int i = 0; i < 6; ++i) {                                                  \
      const float* fp = &featb[(size_t)(k0_ + tgi[i] * 4) * DD + di[i]];           \
      v0[i] = fp[0];                                                               \
      v1[i] = fp[DD];                                                              \
      v2[i] = fp[2 * DD];                                                          \
      v3[i] = fp[3 * DD];                                                          \
    }                                                                              \
  } while (0)

  f32x4 accP[4][3] = {};
  LOADV(0);
  for (int ac = 0; ac < 8; ++ac) {
    #pragma unroll
    for (int i = 0; i < 6; ++i)
      *(uint2*)wp[i] = make_uint2(packrtz(v0[i], v1[i]), packrtz(v2[i], v3[i]));
    __syncthreads();
    if (ac < 7) LOADV(ac + 1);
    fragh pf[4];
    half8 vf[3];
    #pragma unroll
    for (int rt = 0; rt < 4; ++rt)
      pf[rt].u = *(const u32x4*)&sAl[((ac * 4 + g) * QB + rt * 16 + lam) * 8];
    #pragma unroll
    for (int dt = 0; dt < 3; ++dt) {
      int swr = (lam & 1) | (((w * 3 + dt) & 1) << 1);
      vf[dt] = ld_frag8h(&sVt[w * 48 + dt * 16 + lam][(g ^ swr) * 8]);
    }
    __builtin_amdgcn_s_setprio(1);
    #pragma unroll
    for (int rt = 0; rt < 4; ++rt)
      #pragma unroll
      for (int dt = 0; dt < 3; ++dt)
        accP[rt][dt] = MFMA16(pf[rt].h, vf[dt], accP[rt][dt], 0, 0, 0);
    __builtin_amdgcn_s_setprio(0);
    __syncthreads();
  }

  // ---------------- Epilogue: row l2norm over [self|attended], masked pool ----------------
  #pragma unroll
  for (int rt = 0; rt < 4; ++rt)
    #pragma unroll
    for (int rg = 0; rg < 4; ++rg) {
      float s = 0.f;
      #pragma unroll
      for (int dt = 0; dt < 3; ++dt) s += accP[rt][dt][rg] * accP[rt][dt][rg];
      #pragma unroll
      for (int off = 1; off < 16; off <<= 1) s += __shfl_xor(s, off);
      if (lam == 0) sRedM[w][rt * 16 + g * 4 + rg] = s;
    }
  {
    int sr = t >> 3, sc = (t & 7) * 4;
    const float* sp = &selfb[(size_t)sr * DD];
    float ss = 0.f;
    #pragma unroll
    for (int j = 0; j < 12; ++j) {
      float4 v = *(const float4*)&sp[sc + j * 32];
      ss += v.x * v.x + v.y * v.y + v.z * v.z + v.w * v.w;
    }
    ss += __shfl_xor(ss, 1); ss += __shfl_xor(ss, 2); ss += __shfl_xor(ss, 4);
    if ((t & 7) == 0) sSsq[sr] = ss;
  }
  __syncthreads();
  if (t < QB) {
    float tot = sSsq[t];
    #pragma unroll
    for (int ww = 0; ww < 8; ++ww) tot += sRedM[ww][t];
    int mv = msk[(size_t)b * LL + r0 + t];
    sInv[t] = mv ? (1.f / fmaxf(sqrtf(tot), 1e-12f)) : 0.f;
  }
  __syncthreads();
  #pragma unroll
  for (int dt = 0; dt < 3; ++dt) {
    float pa = 0.f;
    #pragma unroll
    for (int rt = 0; rt < 4; ++rt)
      #pragma unroll
      for (int rg = 0; rg < 4; ++rg)
        pa += sInv[rt * 16 + g * 4 + rg] * accP[rt][dt][rg];
    pa += __shfl_xor(pa, 16);
    pa += __shfl_xor(pa, 32);
    if (g == 0) sPool[w * 48 + dt * 16 + lam] = pa;   // unique writer per d
  }
  __syncthreads();
  if (t < DD) {
    float* ac = accum + ((size_t)side * BB + b) * 2 * DD;
    float ps = 0.f;
    const float* sp = selfb + t;
    #pragma unroll 4
    for (int r = 0; r < QB; ++r) ps = fmaf(sInv[r], sp[(size_t)r * DD], ps);
    atomicAdd(&ac[t], ps);
    atomicAdd(&ac[DD + t], sPool[t]);
  }
}

// ---------------- Finalize: divide by mask count, final l2norm ----------------
__global__ __launch_bounds__(256) void finalize_kernel(
    const float* __restrict__ accum, const int* __restrict__ qm,
    const int* __restrict__ am, float* __restrict__ out)
{
  const int b    = blockIdx.x & (BB - 1);
  const int side = blockIdx.x >> 7;
  const int* msk = side ? am : qm;
  const int t = threadIdx.x;
  __shared__ float red[8];

  float c = (float)msk[(size_t)b * LL + t];
  #pragma unroll
  for (int off = 1; off < 64; off <<= 1) c += __shfl_xor(c, off);
  if ((t & 63) == 0) red[t >> 6] = c;
  __syncthreads();
  float cnt = fmaxf(red[0] + red[1] + red[2] + red[3], 1e-9f);

  const float* ac = accum + ((size_t)side * BB + b) * 2 * DD;
  float v[3];
  float ssq = 0.f;
  #pragma unroll
  for (int i = 0; i < 3; ++i) {
    v[i] = ac[t * 3 + i] / cnt;
    ssq += v[i] * v[i];
  }
  #pragma unroll
  for (int off = 1; off < 64; off <<= 1) ssq += __shfl_xor(ssq, off);
  __syncthreads();
  if ((t & 63) == 0) red[t >> 6] = ssq;
  __syncthreads();
  float n = sqrtf(red[0] + red[1] + red[2] + red[3]);
  float inv = 1.f / fmaxf(n, 1e-12f);
  float* ob = out + ((size_t)side * BB + b) * 2 * DD;
  #pragma unroll
  for (int i = 0; i < 3; ++i) ob[t * 3 + i] = v[i] * inv;
}

extern "C" void kernel_launch(void* const* d_in, const int* in_sizes, int n_in,
                              void* d_out, int out_size, void* d_ws, size_t ws_size,
                              hipStream_t stream) {
  const float* qf = (const float*)d_in[0];
  const float* af = (const float*)d_in[1];
  const int*   qm = (const int*)d_in[2];
  const int*   am = (const int*)d_in[3];
  float* out   = (float*)d_out;
  float* accum = (float*)d_ws;   // 2*128*768*4 = 786 KB

  (void)hipMemsetAsync(accum, 0, sizeof(float) * 2 * BB * 2 * DD, stream);
  fused_kernel<<<dim3(1024), 512, 0, stream>>>(qf, af, qm, am, accum);
  finalize_kernel<<<256, 256, 0, stream>>>(accum, qm, am, out);
}